// Round 18
// baseline (611.008 us; speedup 1.0000x reference)
//
#include <hip/hip_runtime.h>
#include <cstdint>
#include <cstddef>

#define BB 4
#define TT 16384
#define CC 512
#define HH 8
#define DD 64
#define MTOT (BB*TT)   // 65536 token rows

typedef __attribute__((ext_vector_type(4))) float f32x4;
typedef __bf16 bf16;
typedef __attribute__((ext_vector_type(8))) bf16 bf16x8;
typedef __attribute__((ext_vector_type(4))) bf16 bf16x4;

static __device__ __forceinline__ float b2f(bf16 x) { return (float)x; }
static __device__ __forceinline__ bf16  f2b(float x) { return (bf16)x; }

// async global->LDS, 16B per lane; dest = wave-uniform base + lane*16
static __device__ __forceinline__ void gload16(const bf16* src, bf16* ldsbase) {
    __builtin_amdgcn_global_load_lds(
        (const __attribute__((address_space(1))) void*)src,
        (__attribute__((address_space(3))) void*)ldsbase, 16, 0, 0);
}

// ---------------------------------------------------------------------------
// Transpose+convert all five 512x512 fp32 weights to bf16 Wt[n][k] = W[k][n].
// VERIFIED r6. grid = 5*256 x 256.
// ---------------------------------------------------------------------------
__global__ __launch_bounds__(256) void transpose_w5(
    const float* __restrict__ W0, const float* __restrict__ W1,
    const float* __restrict__ W2, const float* __restrict__ W3,
    const float* __restrict__ W4,
    bf16* __restrict__ T0, bf16* __restrict__ T1, bf16* __restrict__ T2,
    bf16* __restrict__ T3, bf16* __restrict__ T4)
{
    __shared__ float tile[32][33];
    const int which = blockIdx.x >> 8;
    const float* W = which == 0 ? W0 : which == 1 ? W1 : which == 2 ? W2
                   : which == 3 ? W3 : W4;
    bf16* Wt = which == 0 ? T0 : which == 1 ? T1 : which == 2 ? T2
             : which == 3 ? T3 : T4;
    const int t = blockIdx.x & 255;
    const int r0 = (t >> 4) * 32, c0 = (t & 15) * 32;
    const int tid = threadIdx.x;
    {
        int r = tid >> 3, c4 = (tid & 7) << 2;
        float4 v = *(const float4*)(W + (size_t)(r0 + r) * 512 + c0 + c4);
        tile[r][c4 + 0] = v.x; tile[r][c4 + 1] = v.y;
        tile[r][c4 + 2] = v.z; tile[r][c4 + 3] = v.w;
    }
    __syncthreads();
    {
        int n = tid >> 3, k4 = (tid & 7) << 2;
        bf16x4 o;
        o[0] = f2b(tile[k4 + 0][n]); o[1] = f2b(tile[k4 + 1][n]);
        o[2] = f2b(tile[k4 + 2][n]); o[3] = f2b(tile[k4 + 3][n]);
        *(bf16x4*)(Wt + (size_t)(c0 + n) * 512 + r0 + k4) = o;
    }
}

// ---------------------------------------------------------------------------
// Projection GEMM BODY (MFMA), BK=64 counted-vmcnt. VERIFIED r15/r16/r17.
// v18: + s_setprio(1) around the MFMA cluster (T5).
// MODE 0: fp32 A, fused per-head softmax, store bf16 (Q/K)
// MODE 2: dual fp32 A (K=1024), +bias0+bias1, store bf16 (V)
// MODE 3: bf16 A, +bias, store fp32 (final out)
// ---------------------------------------------------------------------------
template<int MODE>
static __device__ __forceinline__ void gemm_body(
    const float* A0, const float* A1, const bf16* Abf,
    const bf16* Wt0, const bf16* Wt1,
    const float* bias0, const float* bias1,
    bf16* outb, float* outf, int bid,
    bf16* Asm, bf16* BsmAll)
{
    constexpr int KSTEPS = (MODE == 2) ? 16 : 8;   // BK=64

    const int tid = threadIdx.x;
    const int lane = tid & 63;
    const int w = tid >> 6;
    const int l15 = lane & 15, lg = lane >> 4;
    const size_t m0 = (size_t)bid * 128;

    const int arow = tid >> 2, ac16 = (tid & 3) << 4;
    const int blr = lane >> 3;
    const int bsc = ((lane & 7) ^ blr) << 3;

    f32x4 acc[8][4];
#pragma unroll
    for (int m = 0; m < 8; ++m)
#pragma unroll
        for (int n = 0; n < 4; ++n) acc[m][n] = (f32x4){0.f, 0.f, 0.f, 0.f};

    float4 apf[4];   // fp32 A prefetch (MODE0/2)
    bf16x8 apb[2];   // bf16 A prefetch (MODE3)

    auto issueA = [&](int t) {
        if (MODE == 3) {
#pragma unroll
            for (int j = 0; j < 2; ++j)
                apb[j] = *(const bf16x8*)(Abf + (m0 + arow) * CC + (t & 7) * 64
                                          + ac16 + j * 8);
        } else {
            const float* Af = (MODE == 2 && t >= 8) ? A1 : A0;
#pragma unroll
            for (int j = 0; j < 4; ++j)
                apf[j] = *(const float4*)(Af + (m0 + arow) * CC + (t & 7) * 64
                                          + ac16 + j * 4);
        }
    };
    auto writeA = [&]() {
        if (MODE == 3) {
#pragma unroll
            for (int j = 0; j < 2; ++j)
                *(bf16x8*)&Asm[arow * 72 + ac16 + j * 8] = apb[j];
        } else {
#pragma unroll
            for (int j = 0; j < 4; ++j) {
                bf16x4 s;
                s[0] = f2b(apf[j].x); s[1] = f2b(apf[j].y);
                s[2] = f2b(apf[j].z); s[3] = f2b(apf[j].w);
                *(bf16x4*)&Asm[arow * 72 + ac16 + j * 4] = s;
            }
        }
    };
    auto issueB = [&](int t, int buf) {   // 8 gloads/wave, pre-swizzled source
        const bf16* Wt = (MODE == 2 && t >= 8) ? Wt1 : Wt0;
        bf16* bb = BsmAll + buf * (512 * 64);
#pragma unroll
        for (int g = 0; g < 8; ++g) {
            int rowbase = w * 64 + g * 8;
            gload16(Wt + (size_t)(rowbase + blr) * CC + (t & 7) * 64 + bsc,
                    &bb[rowbase * 64]);
        }
    };

    issueA(0);
    issueB(0, 0);
    writeA();
    asm volatile("s_waitcnt lgkmcnt(0)" ::: "memory");

    int cur = 0;
    for (int ko = 0; ko < KSTEPS; ++ko) {
        const bool more = ko + 1 < KSTEPS;
        if (more) { issueA(ko + 1); issueB(ko + 1, cur ^ 1); }
        if (more) {
            if (MODE == 3) asm volatile("s_waitcnt vmcnt(10)" ::: "memory");
            else           asm volatile("s_waitcnt vmcnt(12)" ::: "memory");
        } else {
            asm volatile("s_waitcnt vmcnt(0)" ::: "memory");
        }
        __builtin_amdgcn_s_barrier();
        bf16x8 af[8][2], bfv[4][2];
        const bf16* bb = BsmAll + cur * (512 * 64);
#pragma unroll
        for (int m = 0; m < 8; ++m)
#pragma unroll
            for (int kk = 0; kk < 2; ++kk)
                af[m][kk] = *(const bf16x8*)&Asm[(m * 16 + l15) * 72 + kk * 32 + lg * 8];
#pragma unroll
        for (int n = 0; n < 4; ++n) {
            int row = w * 64 + n * 16 + l15;
            int swz = (l15 & 7) << 3;
#pragma unroll
            for (int kk = 0; kk < 2; ++kk)
                bfv[n][kk] = *(const bf16x8*)&bb[row * 64 + ((kk * 32 + lg * 8) ^ swz)];
        }
        __builtin_amdgcn_s_setprio(1);
#pragma unroll
        for (int kk = 0; kk < 2; ++kk)
#pragma unroll
            for (int m = 0; m < 8; ++m)
#pragma unroll
                for (int n = 0; n < 4; ++n)
                    acc[m][n] = __builtin_amdgcn_mfma_f32_16x16x32_bf16(
                        af[m][kk], bfv[n][kk], acc[m][n], 0, 0, 0);
        __builtin_amdgcn_s_setprio(0);
        __builtin_amdgcn_s_barrier();
        if (more) {
            writeA();
            asm volatile("s_waitcnt lgkmcnt(0)" ::: "memory");
        }
        cur ^= 1;
    }

    // ---- epilogue (VERIFIED) ----
    float bias[4];
#pragma unroll
    for (int n = 0; n < 4; ++n) {
        int col = w * 64 + n * 16 + l15;
        float bvv = bias0 ? bias0[col] : 0.f;
        if (MODE == 2) bvv += bias1[col];
        bias[n] = bvv;
    }
#pragma unroll
    for (int m = 0; m < 8; ++m) {
#pragma unroll
        for (int reg = 0; reg < 4; ++reg) {
            int r = m * 16 + lg * 4 + reg;
            float v0 = acc[m][0][reg] + bias[0];
            float v1 = acc[m][1][reg] + bias[1];
            float v2 = acc[m][2][reg] + bias[2];
            float v3 = acc[m][3][reg] + bias[3];
            if (MODE == 0) {
                float mx = fmaxf(fmaxf(v0, v1), fmaxf(v2, v3));
#pragma unroll
                for (int s = 1; s < 16; s <<= 1) mx = fmaxf(mx, __shfl_xor(mx, s, 64));
                v0 = __expf(v0 - mx); v1 = __expf(v1 - mx);
                v2 = __expf(v2 - mx); v3 = __expf(v3 - mx);
                float sm = v0 + v1 + v2 + v3;
#pragma unroll
                for (int s = 1; s < 16; s <<= 1) sm += __shfl_xor(sm, s, 64);
                float inv = 1.0f / sm;
                v0 *= inv; v1 *= inv; v2 *= inv; v3 *= inv;
            }
            size_t rowoff = (m0 + r) * CC + w * 64 + l15;
            if (MODE == 3) {
                outf[rowoff + 0]  = v0; outf[rowoff + 16] = v1;
                outf[rowoff + 32] = v2; outf[rowoff + 48] = v3;
            } else {
                outb[rowoff + 0]  = f2b(v0); outb[rowoff + 16] = f2b(v1);
                outb[rowoff + 32] = f2b(v2); outb[rowoff + 48] = f2b(v3);
            }
        }
    }
}

// ---------------------------------------------------------------------------
// Fused projection launch: blocks [0,512) K-proj(x2), [512,1024) V-proj,
// [1024,1536) Q-proj(x1). VERIFIED r17.
// ---------------------------------------------------------------------------
__global__ __launch_bounds__(512) void proj_fused(
    const float* x1, const float* x2, const float* y0, const float* y1,
    const bf16* WtQ, const bf16* WtK, const bf16* WtV0, const bf16* WtV1,
    const float* bq, const float* bk, const float* bv0, const float* bv1,
    bf16* Kb, bf16* Vb, bf16* Qb, int which_base)
{
    __shared__ bf16 Asm[128 * 72];
    __shared__ bf16 Bsm[2 * 512 * 64];
    const int which = which_base + ((int)blockIdx.x >> 9);
    const int bid = blockIdx.x & 511;
    if (which == 0)
        gemm_body<0>(x2, nullptr, nullptr, WtK, nullptr, bk, nullptr,
                     Kb, nullptr, bid, Asm, Bsm);
    else if (which == 1)
        gemm_body<2>(y0, y1, nullptr, WtV0, WtV1, bv0, bv1,
                     Vb, nullptr, bid, Asm, Bsm);
    else
        gemm_body<0>(x1, nullptr, nullptr, WtQ, nullptr, bq, nullptr,
                     Qb, nullptr, bid, Asm, Bsm);
}

// Final GEMM (MODE 3), standalone launch (m_base for phased fallback).
__global__ __launch_bounds__(512) void gemm_proj3(
    const bf16* Abf, const bf16* WtP, const float* bp, float* outf, int m_base)
{
    __shared__ bf16 Asm[128 * 72];
    __shared__ bf16 Bsm[2 * 512 * 64];
    gemm_body<3>(nullptr, nullptr, Abf, WtP, nullptr, bp, nullptr,
                 nullptr, outf, blockIdx.x + m_base, Asm, Bsm);
}

// ---------------------------------------------------------------------------
// kv partials, scalar outer-product, float4 LDS reads. v18: 64-t rounds
// (8 barrier-pairs instead of 16; LDS 35 KB, ~4 blocks/CU).
// ---------------------------------------------------------------------------
__global__ __launch_bounds__(256) void kv_partial2(
    const bf16* __restrict__ Kb, const bf16* __restrict__ Vb,
    float* __restrict__ part)
{
    __shared__ float Ks[64][68], Vs[64][68];
    const int tid = threadIdx.x;
    const int bh = blockIdx.x >> 5, chunk = blockIdx.x & 31;
    const int b = bh >> 3, h = bh & 7;
    const size_t base = (size_t)b * TT * CC + h * 64;
    const int d0 = (tid & 15) * 4, e0 = (tid >> 4) * 4;

    float acc[4][4];
#pragma unroll
    for (int i = 0; i < 4; ++i)
#pragma unroll
        for (int j = 0; j < 4; ++j) acc[i][j] = 0.f;
    float ks[4] = {0.f, 0.f, 0.f, 0.f};

    const int tstart = chunk * 512;
    for (int t0 = tstart; t0 < tstart + 512; t0 += 64) {
        __syncthreads();
#pragma unroll
        for (int rep = 0; rep < 4; ++rep) {
            int idx = (tid + rep * 256) * 4;           // [0, 4096)
            int t = idx >> 6, dc = idx & 63;           // t in [0,64)
            const bf16* gk = Kb + base + (size_t)(t0 + t) * CC + dc;
            const bf16* gv = Vb + base + (size_t)(t0 + t) * CC + dc;
            bf16x4 k4 = *(const bf16x4*)gk;
            bf16x4 v4 = *(const bf16x4*)gv;
            *(float4*)&Ks[t][dc] = make_float4(b2f(k4[0]), b2f(k4[1]), b2f(k4[2]), b2f(k4[3]));
            *(float4*)&Vs[t][dc] = make_float4(b2f(v4[0]), b2f(v4[1]), b2f(v4[2]), b2f(v4[3]));
        }
        __syncthreads();
#pragma unroll 8
        for (int tt = 0; tt < 64; ++tt) {
            float4 kf4 = *(const float4*)&Ks[tt][d0];
            float4 vf4 = *(const float4*)&Vs[tt][e0];
            if (e0 == 0) {
                ks[0] += kf4.x; ks[1] += kf4.y; ks[2] += kf4.z; ks[3] += kf4.w;
            }
            acc[0][0] += kf4.x * vf4.x; acc[0][1] += kf4.x * vf4.y;
            acc[0][2] += kf4.x * vf4.z; acc[0][3] += kf4.x * vf4.w;
            acc[1][0] += kf4.y * vf4.x; acc[1][1] += kf4.y * vf4.y;
            acc[1][2] += kf4.y * vf4.z; acc[1][3] += kf4.y * vf4.w;
            acc[2][0] += kf4.z * vf4.x; acc[2][1] += kf4.z * vf4.y;
            acc[2][2] += kf4.z * vf4.z; acc[2][3] += kf4.z * vf4.w;
            acc[3][0] += kf4.w * vf4.x; acc[3][1] += kf4.w * vf4.y;
            acc[3][2] += kf4.w * vf4.z; acc[3][3] += kf4.w * vf4.w;
        }
    }

    float* p = part + (size_t)blockIdx.x * 4160;
#pragma unroll
    for (int i = 0; i < 4; ++i)
#pragma unroll
        for (int j = 0; j < 4; ++j) p[(d0 + i) * 64 + (e0 + j)] = acc[i][j];
    if (tid < 16) {
#pragma unroll
        for (int i = 0; i < 4; ++i) p[4096 + d0 + i] = ks[i];
    }
}

// ---------------------------------------------------------------------------
// Reduce 32 partials per (b,h) -> kvT fp32 [bh][e][d] + ksum. VERIFIED r11.
// ---------------------------------------------------------------------------
__global__ __launch_bounds__(256) void kv_reduce(
    const float* __restrict__ part, float* __restrict__ kvT,
    float* __restrict__ ksum)
{
    const int bh = blockIdx.x >> 3, sl = blockIdx.x & 7;
    const int tid = threadIdx.x;
    const float* p0 = part + (size_t)bh * 32 * 4160;
    const int i0 = sl * 520, i1 = i0 + 520;
    for (int i = i0 + tid; i < i1; i += 256) {
        float s = 0.f;
        for (int c = 0; c < 32; ++c) s += p0[(size_t)c * 4160 + i];
        if (i < 4096) {
            int d = i >> 6, e = i & 63;
            kvT[(size_t)bh * 4096 + e * 64 + d] = s;   // [e][d]
        } else {
            ksum[bh * 64 + (i - 4096)] = s;
        }
    }
}

// ---------------------------------------------------------------------------
// A' = (q @ kv_h) * 1/(q . ksum_h), MFMA. VERIFIED r17. grid = 1024 x 256.
// ---------------------------------------------------------------------------
__global__ __launch_bounds__(256) void qkv_norm_mfma(
    const bf16* Qb, const float* __restrict__ kvT,
    const float* __restrict__ ksum, bf16* Ab)
{
    __shared__ float ksm[8][64];
    const int tid = threadIdx.x;
    const int lane = tid & 63;
    const int w = tid >> 6;
    const int l15 = lane & 15, lg = lane >> 4;
    const size_t t0 = (size_t)blockIdx.x * 64;
    const int b = (int)(t0 / TT);

    for (int i = tid; i < 512; i += 256) ksm[i >> 6][i & 63] = ksum[b * 512 + i];
    __syncthreads();

#pragma unroll
    for (int hi = 0; hi < 2; ++hi) {
        const int h = w + hi * 4;
        const bf16* qbase = Qb + t0 * CC + h * 64;
        const float* kvb = kvT + (size_t)(b * 8 + h) * 4096;   // [e][d] fp32

        f32x4 acc[4][4];
#pragma unroll
        for (int m = 0; m < 4; ++m)
#pragma unroll
            for (int n = 0; n < 4; ++n) acc[m][n] = (f32x4){0.f, 0.f, 0.f, 0.f};
        float dot[4] = {0.f, 0.f, 0.f, 0.f};

#pragma unroll
        for (int ks2 = 0; ks2 < 2; ++ks2) {
            bf16x8 af[4], bfv[4];
#pragma unroll
            for (int m = 0; m < 4; ++m)
                af[m] = *(const bf16x8*)(qbase + (size_t)(m * 16 + l15) * CC
                                         + ks2 * 32 + lg * 8);
#pragma unroll
            for (int n = 0; n < 4; ++n) {
                const float* kr = kvb + (n * 16 + l15) * 64 + ks2 * 32 + lg * 8;
                float4 lo = *(const float4*)(kr + 0);
                float4 hh = *(const float4*)(kr + 4);
                bfv[n][0] = f2b(lo.x); bfv[n][1] = f2b(lo.y);
                bfv[n][2] = f2b(lo.z); bfv[n][3] = f2b(lo.w);
                bfv[n][4] = f2b(hh.x); bfv[n][5] = f2b(hh.y);
                bfv[n][6] = f2b(hh.z); bfv[n][7] = f2b(hh.w);
            }
#pragma unroll
            for (int m = 0; m < 4; ++m) {
                float s = 0.f;
#pragma unroll
                for (int j = 0; j < 8; ++j)
                    s += b2f(af[m][j]) * ksm[h][ks2 * 32 + lg * 8 + j];
                dot[m] += s;
            }
#pragma unroll
            for (int m = 0; m < 4; ++m)
#pragma unroll
                for (int n = 0; n < 4; ++n)
                    acc[m][n] = __builtin_amdgcn_mfma_f32_16x16x32_bf16(
                        af[m], bfv[n], acc[m][n], 0, 0, 0);
        }
#pragma unroll
        for (int m = 0; m < 4; ++m) {
            dot[m] += __shfl_xor(dot[m], 16, 64);
            dot[m] += __shfl_xor(dot[m], 32, 64);
        }
#pragma unroll
        for (int m = 0; m < 4; ++m)
#pragma unroll
            for (int reg = 0; reg < 4; ++reg) {
                float dv = 1.0f / __shfl(dot[m], lg * 4 + reg, 64);
                size_t ro = (t0 + m * 16 + lg * 4 + reg) * CC + h * 64 + l15;
                Ab[ro + 0]  = f2b(acc[m][0][reg] * dv);
                Ab[ro + 16] = f2b(acc[m][1][reg] * dv);
                Ab[ro + 32] = f2b(acc[m][2][reg] * dv);
                Ab[ro + 48] = f2b(acc[m][3][reg] * dv);
            }
    }
}

// ---------------------------------------------------------------------------
extern "C" void kernel_launch(void* const* d_in, const int* in_sizes, int n_in,
                              void* d_out, int out_size, void* d_ws, size_t ws_size,
                              hipStream_t stream)
{
    const float* x1 = (const float*)d_in[0];
    const float* x2 = (const float*)d_in[1];
    const float* y0 = (const float*)d_in[2];
    const float* y1 = (const float*)d_in[3];
    const float* Wq = (const float*)d_in[4];
    const float* bq = (const float*)d_in[5];
    const float* Wk = (const float*)d_in[6];
    const float* bk = (const float*)d_in[7];
    const float* Wv = (const float*)d_in[8];
    const float* bv = (const float*)d_in[9];
    const float* Wp = (const float*)d_in[10];
    const float* bp = (const float*)d_in[11];
    (void)in_sizes; (void)n_in; (void)out_size;

    char* ws = (char*)d_ws;
    size_t off = 0;
    auto alloc = [&](size_t bytes) -> void* {
        void* p = ws + off;
        off += (bytes + 255) & ~(size_t)255;
        return p;
    };
    bf16* WtQ  = (bf16*)alloc((size_t)512 * 512 * 2);
    bf16* WtK  = (bf16*)alloc((size_t)512 * 512 * 2);
    bf16* WtV0 = (bf16*)alloc((size_t)512 * 512 * 2);
    bf16* WtV1 = (bf16*)alloc((size_t)512 * 512 * 2);
    bf16* WtP  = (bf16*)alloc((size_t)512 * 512 * 2);
    float* ksum = (float*)alloc((size_t)32 * 64 * 4);
    float* kvT  = (float*)alloc((size_t)32 * 4096 * 4);
    float* part = (float*)alloc((size_t)1024 * 4160 * 4);
    bf16* Acopy = (bf16*)alloc((size_t)16 * 128 * CC * 2);  // fallback head copy

    const size_t QBYTES = (size_t)MTOT * CC * 2;            // 64 MB
    bf16* Qb_ws = nullptr;
    if (ws_size >= off + QBYTES + 256) Qb_ws = (bf16*)alloc(QBYTES);

    bf16* Kb = (bf16*)d_out;                          // 64 MB scratch in d_out
    bf16* Vb = Kb + (size_t)MTOT * CC;                // second 64 MB
    float* outF = (float*)d_out;

    transpose_w5<<<1280, 256, 0, stream>>>(Wq, Wk, Wv, Wv + (size_t)512 * 512, Wp,
                                           WtQ, WtK, WtV0, WtV1, WtP);

    if (Qb_ws) {
        proj_fused<<<1536, 512, 0, stream>>>(x1, x2, y0, y1, WtQ, WtK, WtV0, WtV1,
                                             bq, bk, bv, bv + 512,
                                             Kb, Vb, Qb_ws, 0);
        kv_partial2<<<1024, 256, 0, stream>>>(Kb, Vb, part);
        kv_reduce<<<256, 256, 0, stream>>>(part, kvT, ksum);
        qkv_norm_mfma<<<1024, 256, 0, stream>>>(Qb_ws, kvT, ksum, Qb_ws);
        gemm_proj3<<<MTOT / 128, 512, 0, stream>>>((const bf16*)Qb_ws, WtP, bp,
                                                   outF, 0);
    } else {
        // Fallback: K,V fused; Q after kv (aliases d_out); phased final.
        bf16* Qb = Kb;
        proj_fused<<<1024, 512, 0, stream>>>(x1, x2, y0, y1, WtQ, WtK, WtV0, WtV1,
                                             bq, bk, bv, bv + 512,
                                             Kb, Vb, Qb, 0);
        kv_partial2<<<1024, 256, 0, stream>>>(Kb, Vb, part);
        kv_reduce<<<256, 256, 0, stream>>>(part, kvT, ksum);
        proj_fused<<<512, 512, 0, stream>>>(x1, x2, y0, y1, WtQ, WtK, WtV0, WtV1,
                                            bq, bk, bv, bv + 512,
                                            Kb, Vb, Qb, 2);
        qkv_norm_mfma<<<1024, 256, 0, stream>>>(Qb, kvT, ksum, Qb);
        hipMemcpyAsync(Acopy, Qb, (size_t)16 * 128 * CC * 2, hipMemcpyDeviceToDevice,
                       stream);
        const int starts[5] = {256, 128, 64, 32, 16};
        const int counts[5] = {256, 128, 64, 32, 16};
        for (int p = 0; p < 5; ++p) {
            gemm_proj3<<<counts[p], 512, 0, stream>>>((const bf16*)Qb, WtP, bp,
                                                      outF, starts[p]);
        }
        gemm_proj3<<<16, 512, 0, stream>>>((const bf16*)Acopy, WtP, bp, outF, 0);
    }
}

// Round 19
// 432.927 us; speedup vs baseline: 1.4113x; 1.4113x over previous
//
#include <hip/hip_runtime.h>
#include <cstdint>
#include <cstddef>

#define BB 4
#define TT 16384
#define CC 512
#define HH 8
#define DD 64
#define MTOT (BB*TT)   // 65536 token rows

typedef __attribute__((ext_vector_type(4))) float f32x4;
typedef __bf16 bf16;
typedef __attribute__((ext_vector_type(8))) bf16 bf16x8;
typedef __attribute__((ext_vector_type(4))) bf16 bf16x4;

static __device__ __forceinline__ float b2f(bf16 x) { return (float)x; }
static __device__ __forceinline__ bf16  f2b(float x) { return (bf16)x; }

// async global->LDS, 16B per lane; dest = wave-uniform base + lane*16
static __device__ __forceinline__ void gload16(const bf16* src, bf16* ldsbase) {
    __builtin_amdgcn_global_load_lds(
        (const __attribute__((address_space(1))) void*)src,
        (__attribute__((address_space(3))) void*)ldsbase, 16, 0, 0);
}

// ---------------------------------------------------------------------------
// Transpose+convert all five 512x512 fp32 weights to bf16 Wt[n][k] = W[k][n].
// VERIFIED r6. grid = 5*256 x 256.
// ---------------------------------------------------------------------------
__global__ __launch_bounds__(256) void transpose_w5(
    const float* __restrict__ W0, const float* __restrict__ W1,
    const float* __restrict__ W2, const float* __restrict__ W3,
    const float* __restrict__ W4,
    bf16* __restrict__ T0, bf16* __restrict__ T1, bf16* __restrict__ T2,
    bf16* __restrict__ T3, bf16* __restrict__ T4)
{
    __shared__ float tile[32][33];
    const int which = blockIdx.x >> 8;
    const float* W = which == 0 ? W0 : which == 1 ? W1 : which == 2 ? W2
                   : which == 3 ? W3 : W4;
    bf16* Wt = which == 0 ? T0 : which == 1 ? T1 : which == 2 ? T2
             : which == 3 ? T3 : T4;
    const int t = blockIdx.x & 255;
    const int r0 = (t >> 4) * 32, c0 = (t & 15) * 32;
    const int tid = threadIdx.x;
    {
        int r = tid >> 3, c4 = (tid & 7) << 2;
        float4 v = *(const float4*)(W + (size_t)(r0 + r) * 512 + c0 + c4);
        tile[r][c4 + 0] = v.x; tile[r][c4 + 1] = v.y;
        tile[r][c4 + 2] = v.z; tile[r][c4 + 3] = v.w;
    }
    __syncthreads();
    {
        int n = tid >> 3, k4 = (tid & 7) << 2;
        bf16x4 o;
        o[0] = f2b(tile[k4 + 0][n]); o[1] = f2b(tile[k4 + 1][n]);
        o[2] = f2b(tile[k4 + 2][n]); o[3] = f2b(tile[k4 + 3][n]);
        *(bf16x4*)(Wt + (size_t)(c0 + n) * 512 + r0 + k4) = o;
    }
}

// ---------------------------------------------------------------------------
// Projection GEMM BODY (MFMA), BK=64 counted-vmcnt. VERIFIED r15/r16/r17.
// (r18's setprio REMOVED — m190-style regression on lockstep loops.)
// MODE 0: fp32 A, fused per-head softmax, store bf16 (Q/K)
// MODE 2: dual fp32 A (K=1024), +bias0+bias1, store bf16 (V)
// MODE 3: bf16 A, +bias, store fp32 (final out)
// ---------------------------------------------------------------------------
template<int MODE>
static __device__ __forceinline__ void gemm_body(
    const float* A0, const float* A1, const bf16* Abf,
    const bf16* Wt0, const bf16* Wt1,
    const float* bias0, const float* bias1,
    bf16* outb, float* outf, int bid,
    bf16* Asm, bf16* BsmAll)
{
    constexpr int KSTEPS = (MODE == 2) ? 16 : 8;   // BK=64

    const int tid = threadIdx.x;
    const int lane = tid & 63;
    const int w = tid >> 6;
    const int l15 = lane & 15, lg = lane >> 4;
    const size_t m0 = (size_t)bid * 128;

    const int arow = tid >> 2, ac16 = (tid & 3) << 4;
    const int blr = lane >> 3;
    const int bsc = ((lane & 7) ^ blr) << 3;

    f32x4 acc[8][4];
#pragma unroll
    for (int m = 0; m < 8; ++m)
#pragma unroll
        for (int n = 0; n < 4; ++n) acc[m][n] = (f32x4){0.f, 0.f, 0.f, 0.f};

    float4 apf[4];   // fp32 A prefetch (MODE0/2)
    bf16x8 apb[2];   // bf16 A prefetch (MODE3)

    auto issueA = [&](int t) {
        if (MODE == 3) {
#pragma unroll
            for (int j = 0; j < 2; ++j)
                apb[j] = *(const bf16x8*)(Abf + (m0 + arow) * CC + (t & 7) * 64
                                          + ac16 + j * 8);
        } else {
            const float* Af = (MODE == 2 && t >= 8) ? A1 : A0;
#pragma unroll
            for (int j = 0; j < 4; ++j)
                apf[j] = *(const float4*)(Af + (m0 + arow) * CC + (t & 7) * 64
                                          + ac16 + j * 4);
        }
    };
    auto writeA = [&]() {
        if (MODE == 3) {
#pragma unroll
            for (int j = 0; j < 2; ++j)
                *(bf16x8*)&Asm[arow * 72 + ac16 + j * 8] = apb[j];
        } else {
#pragma unroll
            for (int j = 0; j < 4; ++j) {
                bf16x4 s;
                s[0] = f2b(apf[j].x); s[1] = f2b(apf[j].y);
                s[2] = f2b(apf[j].z); s[3] = f2b(apf[j].w);
                *(bf16x4*)&Asm[arow * 72 + ac16 + j * 4] = s;
            }
        }
    };
    auto issueB = [&](int t, int buf) {   // 8 gloads/wave, pre-swizzled source
        const bf16* Wt = (MODE == 2 && t >= 8) ? Wt1 : Wt0;
        bf16* bb = BsmAll + buf * (512 * 64);
#pragma unroll
        for (int g = 0; g < 8; ++g) {
            int rowbase = w * 64 + g * 8;
            gload16(Wt + (size_t)(rowbase + blr) * CC + (t & 7) * 64 + bsc,
                    &bb[rowbase * 64]);
        }
    };

    issueA(0);
    issueB(0, 0);
    writeA();
    asm volatile("s_waitcnt lgkmcnt(0)" ::: "memory");

    int cur = 0;
    for (int ko = 0; ko < KSTEPS; ++ko) {
        const bool more = ko + 1 < KSTEPS;
        if (more) { issueA(ko + 1); issueB(ko + 1, cur ^ 1); }
        if (more) {
            if (MODE == 3) asm volatile("s_waitcnt vmcnt(10)" ::: "memory");
            else           asm volatile("s_waitcnt vmcnt(12)" ::: "memory");
        } else {
            asm volatile("s_waitcnt vmcnt(0)" ::: "memory");
        }
        __builtin_amdgcn_s_barrier();
        bf16x8 af[8][2], bfv[4][2];
        const bf16* bb = BsmAll + cur * (512 * 64);
#pragma unroll
        for (int m = 0; m < 8; ++m)
#pragma unroll
            for (int kk = 0; kk < 2; ++kk)
                af[m][kk] = *(const bf16x8*)&Asm[(m * 16 + l15) * 72 + kk * 32 + lg * 8];
#pragma unroll
        for (int n = 0; n < 4; ++n) {
            int row = w * 64 + n * 16 + l15;
            int swz = (l15 & 7) << 3;
#pragma unroll
            for (int kk = 0; kk < 2; ++kk)
                bfv[n][kk] = *(const bf16x8*)&bb[row * 64 + ((kk * 32 + lg * 8) ^ swz)];
        }
#pragma unroll
        for (int kk = 0; kk < 2; ++kk)
#pragma unroll
            for (int m = 0; m < 8; ++m)
#pragma unroll
                for (int n = 0; n < 4; ++n)
                    acc[m][n] = __builtin_amdgcn_mfma_f32_16x16x32_bf16(
                        af[m][kk], bfv[n][kk], acc[m][n], 0, 0, 0);
        __builtin_amdgcn_s_barrier();
        if (more) {
            writeA();
            asm volatile("s_waitcnt lgkmcnt(0)" ::: "memory");
        }
        cur ^= 1;
    }

    // ---- epilogue (VERIFIED) ----
    float bias[4];
#pragma unroll
    for (int n = 0; n < 4; ++n) {
        int col = w * 64 + n * 16 + l15;
        float bvv = bias0 ? bias0[col] : 0.f;
        if (MODE == 2) bvv += bias1[col];
        bias[n] = bvv;
    }
#pragma unroll
    for (int m = 0; m < 8; ++m) {
#pragma unroll
        for (int reg = 0; reg < 4; ++reg) {
            int r = m * 16 + lg * 4 + reg;
            float v0 = acc[m][0][reg] + bias[0];
            float v1 = acc[m][1][reg] + bias[1];
            float v2 = acc[m][2][reg] + bias[2];
            float v3 = acc[m][3][reg] + bias[3];
            if (MODE == 0) {
                float mx = fmaxf(fmaxf(v0, v1), fmaxf(v2, v3));
#pragma unroll
                for (int s = 1; s < 16; s <<= 1) mx = fmaxf(mx, __shfl_xor(mx, s, 64));
                v0 = __expf(v0 - mx); v1 = __expf(v1 - mx);
                v2 = __expf(v2 - mx); v3 = __expf(v3 - mx);
                float sm = v0 + v1 + v2 + v3;
#pragma unroll
                for (int s = 1; s < 16; s <<= 1) sm += __shfl_xor(sm, s, 64);
                float inv = 1.0f / sm;
                v0 *= inv; v1 *= inv; v2 *= inv; v3 *= inv;
            }
            size_t rowoff = (m0 + r) * CC + w * 64 + l15;
            if (MODE == 3) {
                outf[rowoff + 0]  = v0; outf[rowoff + 16] = v1;
                outf[rowoff + 32] = v2; outf[rowoff + 48] = v3;
            } else {
                outb[rowoff + 0]  = f2b(v0); outb[rowoff + 16] = f2b(v1);
                outb[rowoff + 32] = f2b(v2); outb[rowoff + 48] = f2b(v3);
            }
        }
    }
}

// ---------------------------------------------------------------------------
// Fused projection launch: blocks [0,512) K-proj(x2), [512,1024) V-proj,
// [1024,1536) Q-proj(x1). VERIFIED r17.
// ---------------------------------------------------------------------------
__global__ __launch_bounds__(512) void proj_fused(
    const float* x1, const float* x2, const float* y0, const float* y1,
    const bf16* WtQ, const bf16* WtK, const bf16* WtV0, const bf16* WtV1,
    const float* bq, const float* bk, const float* bv0, const float* bv1,
    bf16* Kb, bf16* Vb, bf16* Qb, int which_base)
{
    __shared__ bf16 Asm[128 * 72];
    __shared__ bf16 Bsm[2 * 512 * 64];
    const int which = which_base + ((int)blockIdx.x >> 9);
    const int bid = blockIdx.x & 511;
    if (which == 0)
        gemm_body<0>(x2, nullptr, nullptr, WtK, nullptr, bk, nullptr,
                     Kb, nullptr, bid, Asm, Bsm);
    else if (which == 1)
        gemm_body<2>(y0, y1, nullptr, WtV0, WtV1, bv0, bv1,
                     Vb, nullptr, bid, Asm, Bsm);
    else
        gemm_body<0>(x1, nullptr, nullptr, WtQ, nullptr, bq, nullptr,
                     Qb, nullptr, bid, Asm, Bsm);
}

// Final GEMM (MODE 3), standalone launch (m_base for phased fallback).
__global__ __launch_bounds__(512) void gemm_proj3(
    const bf16* Abf, const bf16* WtP, const float* bp, float* outf, int m_base)
{
    __shared__ bf16 Asm[128 * 72];
    __shared__ bf16 Bsm[2 * 512 * 64];
    gemm_body<3>(nullptr, nullptr, Abf, WtP, nullptr, bp, nullptr,
                 nullptr, outf, blockIdx.x + m_base, Asm, Bsm);
}

// ---------------------------------------------------------------------------
// kv partials, scalar outer-product, float4 LDS reads, 64-t rounds (r18).
// ---------------------------------------------------------------------------
__global__ __launch_bounds__(256) void kv_partial2(
    const bf16* __restrict__ Kb, const bf16* __restrict__ Vb,
    float* __restrict__ part)
{
    __shared__ float Ks[64][68], Vs[64][68];
    const int tid = threadIdx.x;
    const int bh = blockIdx.x >> 5, chunk = blockIdx.x & 31;
    const int b = bh >> 3, h = bh & 7;
    const size_t base = (size_t)b * TT * CC + h * 64;
    const int d0 = (tid & 15) * 4, e0 = (tid >> 4) * 4;

    float acc[4][4];
#pragma unroll
    for (int i = 0; i < 4; ++i)
#pragma unroll
        for (int j = 0; j < 4; ++j) acc[i][j] = 0.f;
    float ks[4] = {0.f, 0.f, 0.f, 0.f};

    const int tstart = chunk * 512;
    for (int t0 = tstart; t0 < tstart + 512; t0 += 64) {
        __syncthreads();
#pragma unroll
        for (int rep = 0; rep < 4; ++rep) {
            int idx = (tid + rep * 256) * 4;           // [0, 4096)
            int t = idx >> 6, dc = idx & 63;           // t in [0,64)
            const bf16* gk = Kb + base + (size_t)(t0 + t) * CC + dc;
            const bf16* gv = Vb + base + (size_t)(t0 + t) * CC + dc;
            bf16x4 k4 = *(const bf16x4*)gk;
            bf16x4 v4 = *(const bf16x4*)gv;
            *(float4*)&Ks[t][dc] = make_float4(b2f(k4[0]), b2f(k4[1]), b2f(k4[2]), b2f(k4[3]));
            *(float4*)&Vs[t][dc] = make_float4(b2f(v4[0]), b2f(v4[1]), b2f(v4[2]), b2f(v4[3]));
        }
        __syncthreads();
#pragma unroll 8
        for (int tt = 0; tt < 64; ++tt) {
            float4 kf4 = *(const float4*)&Ks[tt][d0];
            float4 vf4 = *(const float4*)&Vs[tt][e0];
            if (e0 == 0) {
                ks[0] += kf4.x; ks[1] += kf4.y; ks[2] += kf4.z; ks[3] += kf4.w;
            }
            acc[0][0] += kf4.x * vf4.x; acc[0][1] += kf4.x * vf4.y;
            acc[0][2] += kf4.x * vf4.z; acc[0][3] += kf4.x * vf4.w;
            acc[1][0] += kf4.y * vf4.x; acc[1][1] += kf4.y * vf4.y;
            acc[1][2] += kf4.y * vf4.z; acc[1][3] += kf4.y * vf4.w;
            acc[2][0] += kf4.z * vf4.x; acc[2][1] += kf4.z * vf4.y;
            acc[2][2] += kf4.z * vf4.z; acc[2][3] += kf4.z * vf4.w;
            acc[3][0] += kf4.w * vf4.x; acc[3][1] += kf4.w * vf4.y;
            acc[3][2] += kf4.w * vf4.z; acc[3][3] += kf4.w * vf4.w;
        }
    }

    float* p = part + (size_t)blockIdx.x * 4160;
#pragma unroll
    for (int i = 0; i < 4; ++i)
#pragma unroll
        for (int j = 0; j < 4; ++j) p[(d0 + i) * 64 + (e0 + j)] = acc[i][j];
    if (tid < 16) {
#pragma unroll
        for (int i = 0; i < 4; ++i) p[4096 + d0 + i] = ks[i];
    }
}

// ---------------------------------------------------------------------------
// Reduce 32 partials per (b,h) -> kvT fp32 [bh][e][d] + ksum. VERIFIED r11.
// ---------------------------------------------------------------------------
__global__ __launch_bounds__(256) void kv_reduce(
    const float* __restrict__ part, float* __restrict__ kvT,
    float* __restrict__ ksum)
{
    const int bh = blockIdx.x >> 3, sl = blockIdx.x & 7;
    const int tid = threadIdx.x;
    const float* p0 = part + (size_t)bh * 32 * 4160;
    const int i0 = sl * 520, i1 = i0 + 520;
    for (int i = i0 + tid; i < i1; i += 256) {
        float s = 0.f;
        for (int c = 0; c < 32; ++c) s += p0[(size_t)c * 4160 + i];
        if (i < 4096) {
            int d = i >> 6, e = i & 63;
            kvT[(size_t)bh * 4096 + e * 64 + d] = s;   // [e][d]
        } else {
            ksum[bh * 64 + (i - 4096)] = s;
        }
    }
}

// ---------------------------------------------------------------------------
// A' = (q @ kv_h) * 1/(q . ksum_h), MFMA. VERIFIED r17. grid = 1024 x 256.
// ---------------------------------------------------------------------------
__global__ __launch_bounds__(256) void qkv_norm_mfma(
    const bf16* Qb, const float* __restrict__ kvT,
    const float* __restrict__ ksum, bf16* Ab)
{
    __shared__ float ksm[8][64];
    const int tid = threadIdx.x;
    const int lane = tid & 63;
    const int w = tid >> 6;
    const int l15 = lane & 15, lg = lane >> 4;
    const size_t t0 = (size_t)blockIdx.x * 64;
    const int b = (int)(t0 / TT);

    for (int i = tid; i < 512; i += 256) ksm[i >> 6][i & 63] = ksum[b * 512 + i];
    __syncthreads();

#pragma unroll
    for (int hi = 0; hi < 2; ++hi) {
        const int h = w + hi * 4;
        const bf16* qbase = Qb + t0 * CC + h * 64;
        const float* kvb = kvT + (size_t)(b * 8 + h) * 4096;   // [e][d] fp32

        f32x4 acc[4][4];
#pragma unroll
        for (int m = 0; m < 4; ++m)
#pragma unroll
            for (int n = 0; n < 4; ++n) acc[m][n] = (f32x4){0.f, 0.f, 0.f, 0.f};
        float dot[4] = {0.f, 0.f, 0.f, 0.f};

#pragma unroll
        for (int ks2 = 0; ks2 < 2; ++ks2) {
            bf16x8 af[4], bfv[4];
#pragma unroll
            for (int m = 0; m < 4; ++m)
                af[m] = *(const bf16x8*)(qbase + (size_t)(m * 16 + l15) * CC
                                         + ks2 * 32 + lg * 8);
#pragma unroll
            for (int n = 0; n < 4; ++n) {
                const float* kr = kvb + (n * 16 + l15) * 64 + ks2 * 32 + lg * 8;
                float4 lo = *(const float4*)(kr + 0);
                float4 hh = *(const float4*)(kr + 4);
                bfv[n][0] = f2b(lo.x); bfv[n][1] = f2b(lo.y);
                bfv[n][2] = f2b(lo.z); bfv[n][3] = f2b(lo.w);
                bfv[n][4] = f2b(hh.x); bfv[n][5] = f2b(hh.y);
                bfv[n][6] = f2b(hh.z); bfv[n][7] = f2b(hh.w);
            }
#pragma unroll
            for (int m = 0; m < 4; ++m) {
                float s = 0.f;
#pragma unroll
                for (int j = 0; j < 8; ++j)
                    s += b2f(af[m][j]) * ksm[h][ks2 * 32 + lg * 8 + j];
                dot[m] += s;
            }
#pragma unroll
            for (int m = 0; m < 4; ++m)
#pragma unroll
                for (int n = 0; n < 4; ++n)
                    acc[m][n] = __builtin_amdgcn_mfma_f32_16x16x32_bf16(
                        af[m], bfv[n], acc[m][n], 0, 0, 0);
        }
#pragma unroll
        for (int m = 0; m < 4; ++m) {
            dot[m] += __shfl_xor(dot[m], 16, 64);
            dot[m] += __shfl_xor(dot[m], 32, 64);
        }
#pragma unroll
        for (int m = 0; m < 4; ++m)
#pragma unroll
            for (int reg = 0; reg < 4; ++reg) {
                float dv = 1.0f / __shfl(dot[m], lg * 4 + reg, 64);
                size_t ro = (t0 + m * 16 + lg * 4 + reg) * CC + h * 64 + l15;
                Ab[ro + 0]  = f2b(acc[m][0][reg] * dv);
                Ab[ro + 16] = f2b(acc[m][1][reg] * dv);
                Ab[ro + 32] = f2b(acc[m][2][reg] * dv);
                Ab[ro + 48] = f2b(acc[m][3][reg] * dv);
            }
    }
}

// ---------------------------------------------------------------------------
extern "C" void kernel_launch(void* const* d_in, const int* in_sizes, int n_in,
                              void* d_out, int out_size, void* d_ws, size_t ws_size,
                              hipStream_t stream)
{
    const float* x1 = (const float*)d_in[0];
    const float* x2 = (const float*)d_in[1];
    const float* y0 = (const float*)d_in[2];
    const float* y1 = (const float*)d_in[3];
    const float* Wq = (const float*)d_in[4];
    const float* bq = (const float*)d_in[5];
    const float* Wk = (const float*)d_in[6];
    const float* bk = (const float*)d_in[7];
    const float* Wv = (const float*)d_in[8];
    const float* bv = (const float*)d_in[9];
    const float* Wp = (const float*)d_in[10];
    const float* bp = (const float*)d_in[11];
    (void)in_sizes; (void)n_in; (void)out_size;

    char* ws = (char*)d_ws;
    size_t off = 0;
    auto alloc = [&](size_t bytes) -> void* {
        void* p = ws + off;
        off += (bytes + 255) & ~(size_t)255;
        return p;
    };
    bf16* WtQ  = (bf16*)alloc((size_t)512 * 512 * 2);
    bf16* WtK  = (bf16*)alloc((size_t)512 * 512 * 2);
    bf16* WtV0 = (bf16*)alloc((size_t)512 * 512 * 2);
    bf16* WtV1 = (bf16*)alloc((size_t)512 * 512 * 2);
    bf16* WtP  = (bf16*)alloc((size_t)512 * 512 * 2);
    float* ksum = (float*)alloc((size_t)32 * 64 * 4);
    float* kvT  = (float*)alloc((size_t)32 * 4096 * 4);
    float* part = (float*)alloc((size_t)1024 * 4160 * 4);
    bf16* Acopy = (bf16*)alloc((size_t)16 * 128 * CC * 2);  // fallback head copy

    const size_t QBYTES = (size_t)MTOT * CC * 2;            // 64 MB
    bf16* Qb_ws = nullptr;
    if (ws_size >= off + QBYTES + 256) Qb_ws = (bf16*)alloc(QBYTES);

    bf16* Kb = (bf16*)d_out;                          // 64 MB scratch in d_out
    bf16* Vb = Kb + (size_t)MTOT * CC;                // second 64 MB
    float* outF = (float*)d_out;

    transpose_w5<<<1280, 256, 0, stream>>>(Wq, Wk, Wv, Wv + (size_t)512 * 512, Wp,
                                           WtQ, WtK, WtV0, WtV1, WtP);

    if (Qb_ws) {
        proj_fused<<<1536, 512, 0, stream>>>(x1, x2, y0, y1, WtQ, WtK, WtV0, WtV1,
                                             bq, bk, bv, bv + 512,
                                             Kb, Vb, Qb_ws, 0);
        kv_partial2<<<1024, 256, 0, stream>>>(Kb, Vb, part);
        kv_reduce<<<256, 256, 0, stream>>>(part, kvT, ksum);
        qkv_norm_mfma<<<1024, 256, 0, stream>>>(Qb_ws, kvT, ksum, Qb_ws);
        gemm_proj3<<<MTOT / 128, 512, 0, stream>>>((const bf16*)Qb_ws, WtP, bp,
                                                   outF, 0);
    } else {
        // Fallback: K,V fused; Q after kv (aliases d_out); phased final.
        bf16* Qb = Kb;
        proj_fused<<<1024, 512, 0, stream>>>(x1, x2, y0, y1, WtQ, WtK, WtV0, WtV1,
                                             bq, bk, bv, bv + 512,
                                             Kb, Vb, Qb, 0);
        kv_partial2<<<1024, 256, 0, stream>>>(Kb, Vb, part);
        kv_reduce<<<256, 256, 0, stream>>>(part, kvT, ksum);
        proj_fused<<<512, 512, 0, stream>>>(x1, x2, y0, y1, WtQ, WtK, WtV0, WtV1,
                                            bq, bk, bv, bv + 512,
                                            Kb, Vb, Qb, 2);
        qkv_norm_mfma<<<1024, 256, 0, stream>>>(Qb, kvT, ksum, Qb);
        hipMemcpyAsync(Acopy, Qb, (size_t)16 * 128 * CC * 2, hipMemcpyDeviceToDevice,
                       stream);
        const int starts[5] = {256, 128, 64, 32, 16};
        const int counts[5] = {256, 128, 64, 32, 16};
        for (int p = 0; p < 5; ++p) {
            gemm_proj3<<<counts[p], 512, 0, stream>>>((const bf16*)Qb, WtP, bp,
                                                      outF, starts[p]);
        }
        gemm_proj3<<<16, 512, 0, stream>>>((const bf16*)Acopy, WtP, bp, outF, 0);
    }
}